// Round 2
// baseline (3703.859 us; speedup 1.0000x reference)
//
#include <hip/hip_runtime.h>
#include <stdint.h>

#define T_SEQ 2048
#define HID 4096
#define NHEADS 32
#define I_FF 11008
#define QKV_N 12288
#define GU_N 22016

typedef unsigned short u16;
typedef unsigned int u32;
typedef __attribute__((ext_vector_type(4))) float f32x4;
typedef __attribute__((ext_vector_type(8))) __bf16 bf16x8;
typedef __attribute__((ext_vector_type(4))) u32 u32x4;
typedef __attribute__((ext_vector_type(2))) u32 u32x2;

__device__ __forceinline__ u16 f2bf(float f) {
  union { float f; u32 u; } v; v.f = f;
  u32 u = v.u;
  return (u16)((u + 0x7fffu + ((u >> 16) & 1u)) >> 16);
}
__device__ __forceinline__ float bf2f(u16 h) {
  union { u32 u; float f; } v; v.u = ((u32)h) << 16;
  return v.f;
}
__device__ __forceinline__ u32 pack2(float a, float b) {
  return (u32)f2bf(a) | ((u32)f2bf(b) << 16);
}
__device__ __forceinline__ void split2(float x, u16& hi, u16& lo) {
  hi = f2bf(x);
  lo = f2bf(x - bf2f(hi));
}
// 8 floats -> hi-pack and lo-pack (each 8 bf16 in a u32x4)
__device__ __forceinline__ void split8(const float* v, u32x4& H, u32x4& L) {
#pragma unroll
  for (int j = 0; j < 4; j++) {
    u16 h0, l0, h1, l1;
    split2(v[2 * j], h0, l0);
    split2(v[2 * j + 1], h1, l1);
    H[j] = (u32)h0 | ((u32)h1 << 16);
    L[j] = (u32)l0 | ((u32)l1 << 16);
  }
}

// ---------------- RMSNorm: f32 in -> f32 out ----------------
__global__ __launch_bounds__(256) void rmsnorm_kernel(
    const float* __restrict__ in, const float* __restrict__ w,
    float* __restrict__ out) {
  int row = blockIdx.x;
  const float* x = in + (size_t)row * HID;
  float4 vals[4];
  float ss = 0.f;
#pragma unroll
  for (int k = 0; k < 4; k++) {
    vals[k] = ((const float4*)x)[threadIdx.x + k * 256];
    ss += vals[k].x * vals[k].x + vals[k].y * vals[k].y +
          vals[k].z * vals[k].z + vals[k].w * vals[k].w;
  }
#pragma unroll
  for (int o = 1; o < 64; o <<= 1) ss += __shfl_xor(ss, o);
  __shared__ float red[4];
  if ((threadIdx.x & 63) == 0) red[threadIdx.x >> 6] = ss;
  __syncthreads();
  ss = red[0] + red[1] + red[2] + red[3];
  float rs = rsqrtf(ss * (1.f / HID) + 1e-6f);
#pragma unroll
  for (int k = 0; k < 4; k++) {
    int c4 = threadIdx.x + k * 256;
    float4 wv = ((const float4*)w)[c4];
    float4 o;
    o.x = vals[k].x * rs * wv.x;
    o.y = vals[k].y * rs * wv.y;
    o.z = vals[k].z * rs * wv.z;
    o.w = vals[k].w * rs * wv.w;
    *(float4*)(out + (size_t)row * HID + c4 * 4) = o;
  }
}

// ---------------- AWQ GEMM: A(f32 MxK) @ dequant(W KxN), hi/lo split ----------------
// BM=128 BN=128 BK=32, 4 waves (2x2), mfma_f32_16x16x32_bf16, 3-term split product
template <bool RESID, bool OUTBF16>
__global__ __launch_bounds__(256) void awq_gemm_kernel(
    const float* __restrict__ A, const int* __restrict__ qw,
    const float* __restrict__ scales, const int* __restrict__ qz,
    const float* __restrict__ resid, void* __restrict__ outp,
    int N, int K) {
  __shared__ u16 Ah[128][40], Al[128][40];
  __shared__ u16 Bh[128][40], Bl[128][40];
  int tid = threadIdx.x;
  int wid = tid >> 6, lane = tid & 63;
  int g16 = lane >> 4, l16 = lane & 15;
  int n0 = blockIdx.x * 128;
  int m0 = blockIdx.y * 128;
  int wr = wid >> 1, wc = wid & 1;

  f32x4 acc[4][4] = {};

  int a_row = tid >> 1, a_cb = (tid & 1) * 16;
  int b_col = tid & 127, b_kb = (tid >> 7) * 16;

  int nsteps = K >> 5;
  for (int ks = 0; ks < nsteps; ks++) {
    int k0 = ks << 5;
    __syncthreads();
    // stage A: 128x32 f32 -> hi/lo bf16
    {
      const float* s = A + (size_t)(m0 + a_row) * K + k0 + a_cb;
      float v[16];
      *(float4*)&v[0] = *(const float4*)(s);
      *(float4*)&v[4] = *(const float4*)(s + 4);
      *(float4*)&v[8] = *(const float4*)(s + 8);
      *(float4*)&v[12] = *(const float4*)(s + 12);
      u32x4 H, L;
      split8(&v[0], H, L);
      *(u32x4*)&Ah[a_row][a_cb] = H;
      *(u32x4*)&Al[a_row][a_cb] = L;
      split8(&v[8], H, L);
      *(u32x4*)&Ah[a_row][a_cb + 8] = H;
      *(u32x4*)&Al[a_row][a_cb + 8] = L;
    }
    // stage B: dequant 16 k-values of one column -> hi/lo bf16
    {
      int gidx = (k0 + b_kb) >> 7;
      float sc = scales[(size_t)gidx * N + n0 + b_col];
      float z = (float)qz[(size_t)gidx * N + n0 + b_col];
      const int* qp = qw + (size_t)(k0 + b_kb) * N + n0 + b_col;
      float f[16];
#pragma unroll
      for (int j = 0; j < 16; j++) f[j] = ((float)qp[(size_t)j * N] - z) * sc;
      u32x4 H, L;
      split8(&f[0], H, L);
      *(u32x4*)&Bh[b_col][b_kb] = H;
      *(u32x4*)&Bl[b_col][b_kb] = L;
      split8(&f[8], H, L);
      *(u32x4*)&Bh[b_col][b_kb + 8] = H;
      *(u32x4*)&Bl[b_col][b_kb + 8] = L;
    }
    __syncthreads();
    bf16x8 ah[4], al[4], bh[4], bl[4];
#pragma unroll
    for (int m = 0; m < 4; m++) {
      ah[m] = __builtin_bit_cast(bf16x8,
          *(const u32x4*)&Ah[wr * 64 + m * 16 + l16][g16 * 8]);
      al[m] = __builtin_bit_cast(bf16x8,
          *(const u32x4*)&Al[wr * 64 + m * 16 + l16][g16 * 8]);
    }
#pragma unroll
    for (int n = 0; n < 4; n++) {
      bh[n] = __builtin_bit_cast(bf16x8,
          *(const u32x4*)&Bh[wc * 64 + n * 16 + l16][g16 * 8]);
      bl[n] = __builtin_bit_cast(bf16x8,
          *(const u32x4*)&Bl[wc * 64 + n * 16 + l16][g16 * 8]);
    }
#pragma unroll
    for (int m = 0; m < 4; m++)
#pragma unroll
      for (int n = 0; n < 4; n++) {
        acc[m][n] = __builtin_amdgcn_mfma_f32_16x16x32_bf16(
            ah[m], bh[n], acc[m][n], 0, 0, 0);
        acc[m][n] = __builtin_amdgcn_mfma_f32_16x16x32_bf16(
            al[m], bh[n], acc[m][n], 0, 0, 0);
        acc[m][n] = __builtin_amdgcn_mfma_f32_16x16x32_bf16(
            ah[m], bl[n], acc[m][n], 0, 0, 0);
      }
  }
  // epilogue: C layout col=lane&15, row=(lane>>4)*4+reg
#pragma unroll
  for (int m = 0; m < 4; m++) {
#pragma unroll
    for (int n = 0; n < 4; n++) {
#pragma unroll
      for (int r = 0; r < 4; r++) {
        int row = m0 + wr * 64 + m * 16 + g16 * 4 + r;
        int col = n0 + wc * 64 + n * 16 + l16;
        float v = acc[m][n][r];
        if (RESID) v += resid[(size_t)row * N + col];
        if (OUTBF16)
          ((u16*)outp)[(size_t)row * N + col] = f2bf(v);
        else
          ((float*)outp)[(size_t)row * N + col] = v;
      }
    }
  }
}

// ---------------- RoPE in-place on q,k of qkv (f32) ----------------
__global__ __launch_bounds__(256) void rope_kernel(float* __restrict__ qkv) {
  int t = blockIdx.x;
  __shared__ float cs[64], sn[64];
  if (threadIdx.x < 64) {
    int i = threadIdx.x;
    float freq = exp2f(-(float)i * (13.287712379549449f / 64.f));
    float ang = (float)t * freq;
    cs[i] = cosf(ang);
    sn[i] = sinf(ang);
  }
  __syncthreads();
#pragma unroll
  for (int it = 0; it < 16; it++) {
    int idx = threadIdx.x + it * 256;
    int part = idx >> 11;       // 0=q, 1=k
    int rem = idx & 2047;
    int hh = rem >> 6, i = rem & 63;
    float* base = qkv + (size_t)t * QKV_N + (size_t)part * HID + hh * 128;
    float x1 = base[i], x2 = base[64 + i];
    float c = cs[i], s = sn[i];
    base[i] = x1 * c - x2 * s;
    base[64 + i] = x2 * c + x1 * s;
  }
}

// ---------------- transpose V section of qkv(f32) -> vt[H][T] bf16 ----------------
__global__ __launch_bounds__(256) void transpose_v_kernel(
    const float* __restrict__ qkv, u16* __restrict__ vt) {
  __shared__ u16 tile[64][65];
  int tb = blockIdx.x;   // T/64
  int cb = blockIdx.y;   // H/64
  int tid = threadIdx.x;
  int r = tid >> 2, c16 = (tid & 3) * 16;
  const float* src = qkv + (size_t)(tb * 64 + r) * QKV_N + 2 * HID + cb * 64 + c16;
  float v[16];
  *(float4*)&v[0] = *(const float4*)(src);
  *(float4*)&v[4] = *(const float4*)(src + 4);
  *(float4*)&v[8] = *(const float4*)(src + 8);
  *(float4*)&v[12] = *(const float4*)(src + 12);
#pragma unroll
  for (int i = 0; i < 16; i++) tile[r][c16 + i] = f2bf(v[i]);
  __syncthreads();
  int ocol = tid >> 2, tchunk = (tid & 3) * 16;
  u16 vbuf[16];
#pragma unroll
  for (int i = 0; i < 16; i++) vbuf[i] = tile[tchunk + i][ocol];
  u16* dst = vt + (size_t)(cb * 64 + ocol) * T_SEQ + tb * 64 + tchunk;
  *(u32x4*)dst = *(u32x4*)&vbuf[0];
  *(u32x4*)(dst + 8) = *(u32x4*)&vbuf[8];
}

// ---------------- causal flash attention ----------------
// block = (head, 64 q rows), 4 waves x 16 rows, kv tiles of 32
// q,k in split hi/lo bf16 (fp32-accurate scores); probs/V bf16
__global__ __launch_bounds__(256) void attn_kernel(
    const float* __restrict__ qkv, const u16* __restrict__ vt,
    float* __restrict__ attn_out) {
  constexpr float SCALE = 0.08838834764831845f;  // 1/sqrt(128)
  __shared__ u16 Kh[32][136], Kl[32][136];
  __shared__ u16 Vt_lds[128][40];
  __shared__ u16 P_lds[4][16][40];
  int tid = threadIdx.x;
  int wid = tid >> 6, lane = tid & 63;
  int g16 = lane >> 4, l16 = lane & 15;
  int h = blockIdx.x & 31;
  int qt = blockIdx.x >> 5;
  int qb = qt * 64;

  bf16x8 qh[4], ql[4];
  {
    const float* qsrc = qkv + (size_t)(qb + wid * 16 + l16) * QKV_N + h * 128;
#pragma unroll
    for (int ds = 0; ds < 4; ds++) {
      float v[8];
      *(float4*)&v[0] = *(const float4*)(qsrc + ds * 32 + g16 * 8);
      *(float4*)&v[4] = *(const float4*)(qsrc + ds * 32 + g16 * 8 + 4);
      u32x4 H, L;
      split8(v, H, L);
      qh[ds] = __builtin_bit_cast(bf16x8, H);
      ql[ds] = __builtin_bit_cast(bf16x8, L);
    }
  }
  f32x4 oacc[8] = {};
  float mrun[4] = {-1e30f, -1e30f, -1e30f, -1e30f};
  float lrun[4] = {0.f, 0.f, 0.f, 0.f};

  int st_k = tid >> 3, st_d = (tid & 7) * 16;
  int sv_d = tid >> 1, sv_k = (tid & 1) * 16;

  int ktiles = (qb + 64) >> 5;
  for (int kt = 0; kt < ktiles; kt++) {
    __syncthreads();
    {
      const float* src = qkv + (size_t)(kt * 32 + st_k) * QKV_N + HID + h * 128 + st_d;
      float v[16];
      *(float4*)&v[0] = *(const float4*)(src);
      *(float4*)&v[4] = *(const float4*)(src + 4);
      *(float4*)&v[8] = *(const float4*)(src + 8);
      *(float4*)&v[12] = *(const float4*)(src + 12);
      u32x4 H, L;
      split8(&v[0], H, L);
      *(u32x4*)&Kh[st_k][st_d] = H;
      *(u32x4*)&Kl[st_k][st_d] = L;
      split8(&v[8], H, L);
      *(u32x4*)&Kh[st_k][st_d + 8] = H;
      *(u32x4*)&Kl[st_k][st_d + 8] = L;
    }
    {
      const u16* src = vt + (size_t)(h * 128 + sv_d) * T_SEQ + kt * 32 + sv_k;
      *(u32x4*)&Vt_lds[sv_d][sv_k] = *(const u32x4*)src;
      *(u32x4*)&Vt_lds[sv_d][sv_k + 8] = *(const u32x4*)(src + 8);
    }
    __syncthreads();
    // QK^T with hi/lo split (3-term)
    f32x4 sacc[2] = {};
#pragma unroll
    for (int kb = 0; kb < 2; kb++)
#pragma unroll
      for (int ds = 0; ds < 4; ds++) {
        bf16x8 kfh = __builtin_bit_cast(bf16x8,
            *(const u32x4*)&Kh[kb * 16 + l16][ds * 32 + g16 * 8]);
        bf16x8 kfl = __builtin_bit_cast(bf16x8,
            *(const u32x4*)&Kl[kb * 16 + l16][ds * 32 + g16 * 8]);
        sacc[kb] = __builtin_amdgcn_mfma_f32_16x16x32_bf16(qh[ds], kfh, sacc[kb], 0, 0, 0);
        sacc[kb] = __builtin_amdgcn_mfma_f32_16x16x32_bf16(ql[ds], kfh, sacc[kb], 0, 0, 0);
        sacc[kb] = __builtin_amdgcn_mfma_f32_16x16x32_bf16(qh[ds], kfl, sacc[kb], 0, 0, 0);
      }
    // online softmax (rows r live in regs; keys across 16 lanes)
    float p0v[4], p1v[4];
#pragma unroll
    for (int r = 0; r < 4; r++) {
      int qrow = qb + wid * 16 + g16 * 4 + r;
      bool msk0 = (kt * 32 + l16) > qrow;
      bool msk1 = (kt * 32 + 16 + l16) > qrow;
      float s0 = msk0 ? -1e30f : sacc[0][r] * SCALE;
      float s1 = msk1 ? -1e30f : sacc[1][r] * SCALE;
      float tm = fmaxf(s0, s1);
      tm = fmaxf(tm, __shfl_xor(tm, 1));
      tm = fmaxf(tm, __shfl_xor(tm, 2));
      tm = fmaxf(tm, __shfl_xor(tm, 4));
      tm = fmaxf(tm, __shfl_xor(tm, 8));
      float mnew = fmaxf(mrun[r], tm);
      float fac = __expf(mrun[r] - mnew);
      float p0 = msk0 ? 0.f : __expf(s0 - mnew);
      float p1 = msk1 ? 0.f : __expf(s1 - mnew);
      float ts = p0 + p1;
      ts += __shfl_xor(ts, 1);
      ts += __shfl_xor(ts, 2);
      ts += __shfl_xor(ts, 4);
      ts += __shfl_xor(ts, 8);
      lrun[r] = lrun[r] * fac + ts;
      mrun[r] = mnew;
      p0v[r] = p0; p1v[r] = p1;
#pragma unroll
      for (int db = 0; db < 8; db++) oacc[db][r] *= fac;
    }
    // P -> LDS (transpose to A-fragment layout)
#pragma unroll
    for (int r = 0; r < 4; r++) {
      P_lds[wid][g16 * 4 + r][l16] = f2bf(p0v[r]);
      P_lds[wid][g16 * 4 + r][16 + l16] = f2bf(p1v[r]);
    }
    __syncthreads();
    bf16x8 pa = __builtin_bit_cast(bf16x8, *(const u32x4*)&P_lds[wid][l16][g16 * 8]);
#pragma unroll
    for (int db = 0; db < 8; db++) {
      bf16x8 vb = __builtin_bit_cast(bf16x8,
          *(const u32x4*)&Vt_lds[db * 16 + l16][g16 * 8]);
      oacc[db] = __builtin_amdgcn_mfma_f32_16x16x32_bf16(pa, vb, oacc[db], 0, 0, 0);
    }
  }
#pragma unroll
  for (int r = 0; r < 4; r++) {
    int qrow = qb + wid * 16 + g16 * 4 + r;
    float inv = 1.f / lrun[r];
#pragma unroll
    for (int db = 0; db < 8; db++)
      attn_out[(size_t)qrow * HID + h * 128 + db * 16 + l16] =
          oacc[db][r] * inv;
  }
}

// ---------------- silu(gate)*up : gup bf16 -> act f32 ----------------
__global__ __launch_bounds__(256) void silu_mul_kernel(
    const u16* __restrict__ gu, float* __restrict__ act) {
  size_t e = ((size_t)blockIdx.x * 256 + threadIdx.x) * 8;
  size_t row = e / I_FF;
  int col = (int)(e % I_FF);
  const u16* gp = gu + row * GU_N + col;
  u32x4 gv = *(const u32x4*)gp;
  u32x4 uv = *(const u32x4*)(gp + I_FF);
  float o[8];
#pragma unroll
  for (int j = 0; j < 4; j++) {
    float g0 = bf2f((u16)(gv[j] & 0xffff)), g1 = bf2f((u16)(gv[j] >> 16));
    float u0 = bf2f((u16)(uv[j] & 0xffff)), u1 = bf2f((u16)(uv[j] >> 16));
    o[2 * j] = g0 / (1.f + __expf(-g0)) * u0;
    o[2 * j + 1] = g1 / (1.f + __expf(-g1)) * u1;
  }
  float* dst = act + row * I_FF + col;
  *(float4*)dst = *(float4*)&o[0];
  *(float4*)(dst + 4) = *(float4*)&o[4];
}

extern "C" void kernel_launch(void* const* d_in, const int* in_sizes, int n_in,
                              void* d_out, int out_size, void* d_ws, size_t ws_size,
                              hipStream_t stream) {
  const float* hs    = (const float*)d_in[1];
  const float* ln1   = (const float*)d_in[2];
  const float* ln2   = (const float*)d_in[3];
  const int* qkv_qw  = (const int*)d_in[4];
  const float* qkv_s = (const float*)d_in[5];
  const int* qkv_z   = (const int*)d_in[6];
  const int* o_qw    = (const int*)d_in[7];
  const float* o_s   = (const float*)d_in[8];
  const int* o_z     = (const int*)d_in[9];
  const int* gu_qw   = (const int*)d_in[10];
  const float* gu_s  = (const float*)d_in[11];
  const int* gu_z    = (const int*)d_in[12];
  const int* dn_qw   = (const int*)d_in[13];
  const float* dn_s  = (const float*)d_in[14];
  const int* dn_z    = (const int*)d_in[15];

  char* ws = (char*)d_ws;
  // Buffer plan (with aliasing):
  //   xn   f32 32MB  [ln1 out -> qkv GEMM]   then attn out, then ln2 out
  //   qkv  f32 96MB  [qkv GEMM -> attn]      then act f32 (88MB)
  //   vt   bf16 16MB
  //   hidden f32 32MB
  //   gup  bf16 88MB
  float* xn     = (float*)(ws);
  float* qkv    = (float*)(ws + (size_t)33554432);
  u16*   vt     = (u16*)  (ws + (size_t)33554432 + 100663296);
  float* hidden = (float*)(ws + (size_t)33554432 + 100663296 + 16777216);
  u16*   gup    = (u16*)  (ws + (size_t)33554432 + 100663296 + 16777216 + 33554432);
  float* attn   = xn;    // alias: xn dead after qkv GEMM
  float* act    = qkv;   // alias: qkv dead after attn kernel

  rmsnorm_kernel<<<T_SEQ, 256, 0, stream>>>(hs, ln1, xn);
  awq_gemm_kernel<false, false><<<dim3(QKV_N / 128, T_SEQ / 128), 256, 0, stream>>>(
      xn, qkv_qw, qkv_s, qkv_z, nullptr, qkv, QKV_N, HID);
  rope_kernel<<<T_SEQ, 256, 0, stream>>>(qkv);
  transpose_v_kernel<<<dim3(T_SEQ / 64, HID / 64), 256, 0, stream>>>(qkv, vt);
  attn_kernel<<<NHEADS * (T_SEQ / 64), 256, 0, stream>>>(qkv, vt, attn);
  awq_gemm_kernel<true, false><<<dim3(HID / 128, T_SEQ / 128), 256, 0, stream>>>(
      attn, o_qw, o_s, o_z, hs, hidden, HID, HID);
  rmsnorm_kernel<<<T_SEQ, 256, 0, stream>>>(hidden, ln2, xn);
  awq_gemm_kernel<false, true><<<dim3(GU_N / 128, T_SEQ / 128), 256, 0, stream>>>(
      xn, gu_qw, gu_s, gu_z, nullptr, gup, GU_N, HID);
  silu_mul_kernel<<<(T_SEQ * (size_t)I_FF / 8 / 256), 256, 0, stream>>>(gup, act);
  awq_gemm_kernel<true, false><<<dim3(HID / 128, T_SEQ / 128), 256, 0, stream>>>(
      act, dn_qw, dn_s, dn_z, hidden, (float*)d_out, HID, I_FF);
}